// Round 1
// baseline (576.657 us; speedup 1.0000x reference)
//
#include <hip/hip_runtime.h>
#include <hip/hip_bf16.h>

// Problem constants
#define S_LEN   2048
#define BATCH   4
#define DMODEL  1024
#define NHEAD   16
#define DHEAD   64
#define MROWS   (S_LEN * BATCH)   // 8192 rows in flattened (s,b) order

typedef __bf16 bf16;
typedef __bf16 bf16x8 __attribute__((ext_vector_type(8)));
typedef float  f32x4  __attribute__((ext_vector_type(4)));

// ---------------------------------------------------------------------------
// fp32 -> bf16 cast, 8 elems/thread
// ---------------------------------------------------------------------------
__global__ __launch_bounds__(256) void cast_bf16(const float* __restrict__ in,
                                                 bf16* __restrict__ out, int n8) {
    int i = blockIdx.x * 256 + threadIdx.x;
    if (i >= n8) return;
    const float4* p = (const float4*)in;
    float4 a = p[i * 2], b = p[i * 2 + 1];
    bf16x8 o;
    o[0] = (bf16)a.x; o[1] = (bf16)a.y; o[2] = (bf16)a.z; o[3] = (bf16)a.w;
    o[4] = (bf16)b.x; o[5] = (bf16)b.y; o[6] = (bf16)b.z; o[7] = (bf16)b.w;
    *(bf16x8*)(out + (size_t)i * 8) = o;
}

// ---------------------------------------------------------------------------
// C[M,N] = A[M,K] * W[N,K]^T + bias[N]
// M=8192, N=K=1024. 128x128 tile, BK=32, 256 threads (4 waves, 64x64/wave),
// mfma_f32_16x16x32_bf16. LDS row stride 40 bf16 = 80 B (16B aligned, 2-way
// bank aliasing only -> free).
// ---------------------------------------------------------------------------
template <typename OUT_T>
__global__ __launch_bounds__(256) void gemm_bt(const bf16* __restrict__ A,
                                               const bf16* __restrict__ W,
                                               const float* __restrict__ bias,
                                               OUT_T* __restrict__ C) {
    constexpr int M = MROWS, N = DMODEL, K = DMODEL;
    constexpr int BM = 128, BN = 128, BK = 32, LDA = 40;
    __shared__ __align__(16) bf16 sA[BM * LDA];
    __shared__ __align__(16) bf16 sB[BN * LDA];

    const int t    = threadIdx.x;
    const int lane = t & 63;
    const int wave = t >> 6;
    const int bm = blockIdx.y * BM;
    const int bn = blockIdx.x * BN;
    const int wm = (wave & 1) * 64;
    const int wn = (wave >> 1) * 64;
    const int lq = lane & 15;          // row-within-tile for A/B frags
    const int lg = lane >> 4;          // k-chunk selector (0..3)

    // staging assignment: 4 threads per row, 8 bf16 (16B) each
    const int lrow = t >> 2;           // 0..63
    const int lcol = (t & 3) * 8;      // 0,8,16,24

    f32x4 acc[4][4] = {};

    for (int k0 = 0; k0 < K; k0 += BK) {
        const bf16* Ap = A + (size_t)(bm + lrow) * K + k0 + lcol;
        const bf16* Wp = W + (size_t)(bn + lrow) * K + k0 + lcol;
        bf16x8 a0 = *(const bf16x8*)Ap;
        bf16x8 a1 = *(const bf16x8*)(Ap + (size_t)64 * K);
        bf16x8 b0 = *(const bf16x8*)Wp;
        bf16x8 b1 = *(const bf16x8*)(Wp + (size_t)64 * K);
        *(bf16x8*)&sA[lrow * LDA + lcol]        = a0;
        *(bf16x8*)&sA[(lrow + 64) * LDA + lcol] = a1;
        *(bf16x8*)&sB[lrow * LDA + lcol]        = b0;
        *(bf16x8*)&sB[(lrow + 64) * LDA + lcol] = b1;
        __syncthreads();

        const int koff = lg * 8;       // covers k0..k0+31 across the 4 lane groups
        bf16x8 af[4], bfr[4];
#pragma unroll
        for (int mt = 0; mt < 4; mt++)
            af[mt] = *(const bf16x8*)&sA[(wm + mt * 16 + lq) * LDA + koff];
#pragma unroll
        for (int nt = 0; nt < 4; nt++)
            bfr[nt] = *(const bf16x8*)&sB[(wn + nt * 16 + lq) * LDA + koff];
#pragma unroll
        for (int mt = 0; mt < 4; mt++)
#pragma unroll
            for (int nt = 0; nt < 4; nt++)
                acc[mt][nt] = __builtin_amdgcn_mfma_f32_16x16x32_bf16(
                    af[mt], bfr[nt], acc[mt][nt], 0, 0, 0);
        __syncthreads();
    }

    // Epilogue. C/D layout: col = lane&15, row = (lane>>4)*4 + r  [m89]
    const int cr = lg * 4;
    const int cc = lq;
#pragma unroll
    for (int nt = 0; nt < 4; nt++) {
        const int col = bn + wn + nt * 16 + cc;
        const float bv = bias[col];
#pragma unroll
        for (int mt = 0; mt < 4; mt++) {
            const int row = bm + wm + mt * 16 + cr;
#pragma unroll
            for (int r = 0; r < 4; r++) {
                float v = acc[mt][nt][r] + bv;
                C[(size_t)(row + r) * N + col] = (OUT_T)v;
            }
        }
    }
}

// ---------------------------------------------------------------------------
// Flash attention, causal + zero-sink. One block per (b, h, q-tile of 64).
// 256 threads = 4 waves; wave w owns q rows [w*16, w*16+16).
// Sink handled analytically: init m=0, l=1 (key with score 0, value 0).
// ---------------------------------------------------------------------------
__global__ __launch_bounds__(256) void attn_kernel(const bf16* __restrict__ Q,
                                                   const bf16* __restrict__ Km,
                                                   const bf16* __restrict__ V,
                                                   const float* __restrict__ beta,
                                                   bf16* __restrict__ O) {
    constexpr int QT = 64, KT = 64, LD = 72;   // 144 B stride: 16B aligned, 2-way-free banks
    __shared__ __align__(16) bf16 sQ[QT * LD];
    __shared__ __align__(16) bf16 sK[KT * LD];
    __shared__ __align__(16) bf16 sVt[DHEAD * LD];   // sVt[d][k] = V[k][d]
    __shared__ __align__(16) bf16 sP[QT * LD];       // per-wave 16-row slices

    const int t    = threadIdx.x;
    const int lane = t & 63;
    const int wave = t >> 6;
    const int qi = (int)gridDim.x - 1 - (int)blockIdx.x;  // heavy tiles first
    const int h = blockIdx.y;
    const int b = blockIdx.z;
    const int qb = qi * QT;
    const float sf = 1.0f / (expf(beta[h]) * 8.0f);       // 8 = sqrt(DH)

    const int lq = lane & 15;
    const int lg = lane >> 4;

    // load Q tile (64 rows x 64 dh)
    for (int c = t; c < 512; c += 256) {
        int r = c >> 3, d8 = (c & 7) * 8;
        *(bf16x8*)&sQ[r * LD + d8] =
            *(const bf16x8*)&Q[((size_t)((qb + r) * BATCH + b)) * DMODEL + h * DHEAD + d8];
    }

    float m_r[4], l_r[4];
    f32x4 o_acc[4] = {};          // o_acc[dt][r]: row = lg*4+r, col(dh) = dt*16+lq
#pragma unroll
    for (int r = 0; r < 4; r++) { m_r[r] = 0.0f; l_r[r] = 1.0f; }

    for (int kt = 0; kt <= qi; kt++) {
        const int kb = kt * KT;
        __syncthreads();   // prev-iter compute done (and Q visible on iter 0)
        for (int c = t; c < 512; c += 256) {
            int r = c >> 3, d8 = (c & 7) * 8;
            size_t g = ((size_t)((kb + r) * BATCH + b)) * DMODEL + h * DHEAD + d8;
            *(bf16x8*)&sK[r * LD + d8] = *(const bf16x8*)&Km[g];
            bf16x8 vv = *(const bf16x8*)&V[g];
#pragma unroll
            for (int j = 0; j < 8; j++) sVt[(d8 + j) * LD + r] = vv[j];
        }
        __syncthreads();

        // scores: 16 q-rows (this wave) x 64 keys
        f32x4 s_acc[4] = {};
#pragma unroll
        for (int kc = 0; kc < 2; kc++) {
            bf16x8 aq = *(const bf16x8*)&sQ[(wave * 16 + lq) * LD + kc * 32 + lg * 8];
#pragma unroll
            for (int nt = 0; nt < 4; nt++) {
                bf16x8 bk = *(const bf16x8*)&sK[(nt * 16 + lq) * LD + kc * 32 + lg * 8];
                s_acc[nt] = __builtin_amdgcn_mfma_f32_16x16x32_bf16(aq, bk, s_acc[nt], 0, 0, 0);
            }
        }

        const bool diag = (kt == qi);
#pragma unroll
        for (int nt = 0; nt < 4; nt++)
#pragma unroll
            for (int r = 0; r < 4; r++) {
                float sv = s_acc[nt][r] * sf;
                if (diag && (nt * 16 + lq) > (wave * 16 + lg * 4 + r)) sv = -1e30f;
                s_acc[nt][r] = sv;
            }

        // online softmax per row r (row data lives in the 16-lane group)
#pragma unroll
        for (int r = 0; r < 4; r++) {
            float mx = fmaxf(fmaxf(s_acc[0][r], s_acc[1][r]),
                             fmaxf(s_acc[2][r], s_acc[3][r]));
#pragma unroll
            for (int off = 1; off < 16; off <<= 1) mx = fmaxf(mx, __shfl_xor(mx, off));
            float mnew  = fmaxf(m_r[r], mx);
            float alpha = __expf(m_r[r] - mnew);
            float ssum = 0.0f;
#pragma unroll
            for (int nt = 0; nt < 4; nt++) {
                float p = __expf(s_acc[nt][r] - mnew);
                s_acc[nt][r] = p;
                ssum += p;
            }
#pragma unroll
            for (int off = 1; off < 16; off <<= 1) ssum += __shfl_xor(ssum, off);
            l_r[r] = l_r[r] * alpha + ssum;
            m_r[r] = mnew;
#pragma unroll
            for (int dt = 0; dt < 4; dt++) o_acc[dt][r] *= alpha;
        }

        // P: C-layout -> LDS -> A-layout (per-wave private region, no barrier)
#pragma unroll
        for (int nt = 0; nt < 4; nt++)
#pragma unroll
            for (int r = 0; r < 4; r++)
                sP[(wave * 16 + lg * 4 + r) * LD + nt * 16 + lq] = (bf16)s_acc[nt][r];

        // O += P * V
#pragma unroll
        for (int kc = 0; kc < 2; kc++) {
            bf16x8 ap = *(const bf16x8*)&sP[(wave * 16 + lq) * LD + kc * 32 + lg * 8];
#pragma unroll
            for (int dt = 0; dt < 4; dt++) {
                bf16x8 bv = *(const bf16x8*)&sVt[(dt * 16 + lq) * LD + kc * 32 + lg * 8];
                o_acc[dt] = __builtin_amdgcn_mfma_f32_16x16x32_bf16(ap, bv, o_acc[dt], 0, 0, 0);
            }
        }
    }

    // epilogue: O[s,b,h*64+d] = o_acc / l
#pragma unroll
    for (int dt = 0; dt < 4; dt++)
#pragma unroll
        for (int r = 0; r < 4; r++) {
            int srow = qb + wave * 16 + lg * 4 + r;
            int d = h * DHEAD + dt * 16 + lq;
            O[((size_t)(srow * BATCH + b)) * DMODEL + d] = (bf16)(o_acc[dt][r] / l_r[r]);
        }
}

// ---------------------------------------------------------------------------
extern "C" void kernel_launch(void* const* d_in, const int* in_sizes, int n_in,
                              void* d_out, int out_size, void* d_ws, size_t ws_size,
                              hipStream_t stream) {
    const float* x    = (const float*)d_in[0];
    // d_in[1] = attn_mask (pure causal -1e9; implemented structurally)
    const float* beta = (const float*)d_in[2];
    const float* Wq   = (const float*)d_in[3];
    const float* bq   = (const float*)d_in[4];
    const float* Wk   = (const float*)d_in[5];
    const float* bk   = (const float*)d_in[6];
    const float* Wv   = (const float*)d_in[7];
    const float* bv   = (const float*)d_in[8];
    const float* Wo   = (const float*)d_in[9];
    const float* bo   = (const float*)d_in[10];
    float* out = (float*)d_out;

    char* ws = (char*)d_ws;
    size_t off = 0;
    auto alloc = [&](size_t bytes) -> void* {
        void* p = ws + off;
        off += (bytes + 255) & ~(size_t)255;
        return p;
    };
    const size_t xbytes = (size_t)MROWS * DMODEL * sizeof(bf16);   // 16 MB
    const size_t wbytes = (size_t)DMODEL * DMODEL * sizeof(bf16);  // 2 MB
    bf16* xb  = (bf16*)alloc(xbytes);
    bf16* wqb = (bf16*)alloc(wbytes);
    bf16* wkb = (bf16*)alloc(wbytes);
    bf16* wvb = (bf16*)alloc(wbytes);
    bf16* wob = (bf16*)alloc(wbytes);
    bf16* qws = (bf16*)alloc(xbytes);
    bf16* kws = (bf16*)alloc(xbytes);
    bf16* vws = (bf16*)alloc(xbytes);
    bf16* aob = (bf16*)alloc(xbytes);

    const int nx8 = MROWS * DMODEL / 8;      // 1M threads
    const int nw8 = DMODEL * DMODEL / 8;     // 128K threads
    cast_bf16<<<(nx8 + 255) / 256, 256, 0, stream>>>(x, xb, nx8);
    cast_bf16<<<(nw8 + 255) / 256, 256, 0, stream>>>(Wq, wqb, nw8);
    cast_bf16<<<(nw8 + 255) / 256, 256, 0, stream>>>(Wk, wkb, nw8);
    cast_bf16<<<(nw8 + 255) / 256, 256, 0, stream>>>(Wv, wvb, nw8);
    cast_bf16<<<(nw8 + 255) / 256, 256, 0, stream>>>(Wo, wob, nw8);

    dim3 ggrid(DMODEL / 128, MROWS / 128);   // (8, 64)
    gemm_bt<bf16><<<ggrid, 256, 0, stream>>>(xb, wqb, bq, qws);
    gemm_bt<bf16><<<ggrid, 256, 0, stream>>>(xb, wkb, bk, kws);
    gemm_bt<bf16><<<ggrid, 256, 0, stream>>>(xb, wvb, bv, vws);

    dim3 agrid(S_LEN / 64, NHEAD, BATCH);    // (32, 16, 4)
    attn_kernel<<<agrid, 256, 0, stream>>>(qws, kws, vws, beta, aob);

    gemm_bt<float><<<ggrid, 256, 0, stream>>>(aob, wob, bo, out);
}